// Round 1
// baseline (10926.469 us; speedup 1.0000x reference)
//
#include <hip/hip_runtime.h>
#include <math.h>

// Problem constants
#define T_STEPS 512
#define TAPE_N  30
#define HD      1024
#define G4      4096
#define LSTRIDE 4194304   // 4096*1024, per-layer stride of w_ih / w_hh

__device__ __forceinline__ float sigf(float x) { return 1.0f / (1.0f + expf(-x)); }

// ---------------------------------------------------------------------------
// Generic GEMM: Out[m*ldo + n] = sum_k A[n*1024 + k] * X[m*ldx + k] (+ b1[n] + b2[n])
// K fixed = 1024. Grid: (N/64, ceil(M/64)), block 256. Each thread 4x4.
// ---------------------------------------------------------------------------
__global__ __launch_bounds__(256) void gemm_nt(
    const float* __restrict__ A, const float* __restrict__ X, float* __restrict__ Out,
    const float* __restrict__ b1, const float* __restrict__ b2,
    int M, int ldx, int ldo)
{
  __shared__ float As[64][65];
  __shared__ float Xs[64][65];
  const int tid = threadIdx.x;
  const int tn = tid & 15, tm = tid >> 4;
  const int bn = blockIdx.x * 64, bm = blockIdx.y * 64;
  float acc[4][4];
  #pragma unroll
  for (int i = 0; i < 4; ++i)
    #pragma unroll
    for (int j = 0; j < 4; ++j) acc[i][j] = 0.f;

  for (int k0 = 0; k0 < 1024; k0 += 64) {
    #pragma unroll
    for (int r = 0; r < 4; ++r) {
      int linear = r * 1024 + tid * 4;
      int nn = linear >> 6, kk = linear & 63;
      float4 av = *(const float4*)(A + (size_t)(bn + nn) * 1024 + k0 + kk);
      As[nn][kk+0] = av.x; As[nn][kk+1] = av.y; As[nn][kk+2] = av.z; As[nn][kk+3] = av.w;
      float4 xv = make_float4(0.f, 0.f, 0.f, 0.f);
      if (bm + nn < M) xv = *(const float4*)(X + (size_t)(bm + nn) * ldx + k0 + kk);
      Xs[nn][kk+0] = xv.x; Xs[nn][kk+1] = xv.y; Xs[nn][kk+2] = xv.z; Xs[nn][kk+3] = xv.w;
    }
    __syncthreads();
    #pragma unroll 16
    for (int kk = 0; kk < 64; ++kk) {
      float av[4], xv[4];
      #pragma unroll
      for (int u = 0; u < 4; ++u) { av[u] = As[tn*4+u][kk]; xv[u] = Xs[tm*4+u][kk]; }
      #pragma unroll
      for (int i = 0; i < 4; ++i)
        #pragma unroll
        for (int j = 0; j < 4; ++j) acc[i][j] += xv[i] * av[j];
    }
    __syncthreads();
  }
  #pragma unroll
  for (int i = 0; i < 4; ++i) {
    int m = bm + tm * 4 + i;
    if (m >= M) continue;
    #pragma unroll
    for (int j = 0; j < 4; ++j) {
      int n = bn + tn * 4 + j;
      float r = acc[i][j];
      if (b1) r += b1[n];
      if (b2) r += b2[n];
      Out[(size_t)m * ldo + n] = r;
    }
  }
}

// ---------------------------------------------------------------------------
// Extract diagonals of attn_wh / attn_wht -> diag[0:2048]=dwh, diag[2048:4096]=dwht
// ---------------------------------------------------------------------------
__global__ void diag_k(const float* __restrict__ wh, const float* __restrict__ wht,
                       float* __restrict__ diag)
{
  int i = blockIdx.x * 256 + threadIdx.x;
  if (i < 2048) {
    int l = i >> 10, h = i & 1023;
    size_t idx = (size_t)l * 1048576 + (size_t)h * 1025;
    diag[i]        = wh[idx];
    diag[2048 + i] = wht[idx];
  }
}

// ---------------------------------------------------------------------------
// Phase-1 layer 0: from XI0[t] (gates with biases, h_prev=c_prev=0) -> tape slot t, h0p1
// ---------------------------------------------------------------------------
__global__ __launch_bounds__(256) void phase1_l0_k(const float* __restrict__ XI0,
    float* __restrict__ tapeh, float* __restrict__ tapec, float* __restrict__ h0p1)
{
  int t = blockIdx.x;
  #pragma unroll
  for (int r = 0; r < 4; ++r) {
    int c = threadIdx.x + r * 256;
    float gi = XI0[t*4096 + c];
    float gg = XI0[t*4096 + 2048 + c];
    float go = XI0[t*4096 + 3072 + c];
    float cc = sigf(gi) * tanhf(gg);      // c_prev = 0
    float hh = sigf(go) * tanhf(cc);
    tapeh[t*2048 + c] = hh;
    tapec[t*2048 + c] = cc;
    h0p1[t*1024 + c] = hh;
  }
}

// Phase-1 layer 1: from G1[t] (w_ih1@h0 + biases) -> tape slot t layer 1
__global__ __launch_bounds__(256) void phase1_l1_k(const float* __restrict__ G1,
    float* __restrict__ tapeh, float* __restrict__ tapec)
{
  int t = blockIdx.x;
  #pragma unroll
  for (int r = 0; r < 4; ++r) {
    int c = threadIdx.x + r * 256;
    float gi = G1[t*4096 + c];
    float gg = G1[t*4096 + 2048 + c];
    float go = G1[t*4096 + 3072 + c];
    float cc = sigf(gi) * tanhf(gg);
    float hh = sigf(go) * tanhf(cc);
    tapeh[t*2048 + 1024 + c] = hh;
    tapec[t*2048 + 1024 + c] = cc;
  }
}

// ---------------------------------------------------------------------------
// Scan kernel A (grid 316 x 256):
//   WG 0..59   : scores[l*30+s] = sum_h v[l,h]*tanh(dwh*tape_h[s,l,h] + XA[t,l,h] + dwht*prevh[l,h])
//   WG 60..315 : P{0,1}[(t-1)%30][row] = w_hh{0,1}[row,:] @ tape_h[(t-1)%30, {0,1}, :]
// ---------------------------------------------------------------------------
__global__ __launch_bounds__(256) void scanA_k(
    const float* __restrict__ tapeh, const float* __restrict__ XA,
    const float* __restrict__ newh, const float* __restrict__ diag,
    const float* __restrict__ attn_v, const float* __restrict__ w_hh,
    float* __restrict__ scores, float* __restrict__ P0, float* __restrict__ P1, int t)
{
  int wg = blockIdx.x;
  if (wg < 60) {
    int l = wg / 30, s = wg % 30;
    const float* dwh  = diag + l * 1024;
    const float* dwht = diag + 2048 + l * 1024;
    const float* th   = tapeh + s * 2048 + l * 1024;
    const float* xa   = XA + (size_t)t * 2048 + l * 1024;
    const float* ph   = newh + ((t - 1) & 1) * 2048 + l * 1024;
    const float* vv   = attn_v + l * 1024;
    float partial = 0.f;
    #pragma unroll
    for (int r = 0; r < 4; ++r) {
      int h = threadIdx.x + r * 256;
      float a = tanhf(dwh[h] * th[h] + xa[h] + dwht[h] * ph[h]);
      partial += a * vv[h];
    }
    #pragma unroll
    for (int o = 32; o >= 1; o >>= 1) partial += __shfl_down(partial, o, 64);
    __shared__ float red[4];
    if ((threadIdx.x & 63) == 0) red[threadIdx.x >> 6] = partial;
    __syncthreads();
    if (threadIdx.x == 0) scores[l * 30 + s] = red[0] + red[1] + red[2] + red[3];
  } else {
    int w = wg - 60;                 // 0..255 -> rows w*16 .. w*16+15
    int slot = (t - 1) % 30;
    __shared__ float hs[2048];
    for (int i = threadIdx.x; i < 512; i += 256)
      ((float4*)hs)[i] = ((const float4*)(tapeh + slot * 2048))[i];
    __syncthreads();
    int row  = w * 16 + (threadIdx.x >> 4);
    int lane = threadIdx.x & 15;
    #pragma unroll
    for (int mat = 0; mat < 2; ++mat) {
      const float* wr = w_hh + (size_t)mat * LSTRIDE + (size_t)row * 1024;
      const float* hv = hs + mat * 1024;
      float acc = 0.f;
      #pragma unroll
      for (int k = 0; k < 16; ++k) {
        float4 wv = *(const float4*)(wr + lane * 4 + k * 64);
        float4 h4 = *(const float4*)(hv + lane * 4 + k * 64);
        acc += wv.x * h4.x + wv.y * h4.y + wv.z * h4.z + wv.w * h4.w;
      }
      #pragma unroll
      for (int o = 8; o >= 1; o >>= 1) acc += __shfl_xor(acc, o, 64);
      if (lane == 0) { (mat ? P1 : P0)[slot * 4096 + row] = acc; }
    }
  }
}

// ---------------------------------------------------------------------------
// Scan kernel B (grid 64 x 64): softmax, layer-0 gates via P0, h0/c0, new_h both
// layers (-> prevh parity buffer), new_c1, u1 = sum_s a1[s]*P1[s][row]
// ---------------------------------------------------------------------------
__global__ __launch_bounds__(64) void scanB_k(
    const float* __restrict__ scores, const float* __restrict__ XI0,
    const float* __restrict__ P0, const float* __restrict__ P1,
    float* __restrict__ tapeh, float* __restrict__ tapec,
    float* __restrict__ h0cur, float* __restrict__ u1b,
    float* __restrict__ newh, float* __restrict__ newc1, int t)
{
  const int tid = threadIdx.x;
  const int j0 = blockIdx.x * 16;

  // softmax over tape dim, both layers (redundant per thread; cheap)
  float a0[TAPE_N], a1[TAPE_N];
  {
    float m0 = -1e30f, m1 = -1e30f;
    #pragma unroll
    for (int s = 0; s < TAPE_N; ++s) {
      m0 = fmaxf(m0, scores[s]);
      m1 = fmaxf(m1, scores[30 + s]);
    }
    float s0 = 0.f, s1 = 0.f;
    #pragma unroll
    for (int s = 0; s < TAPE_N; ++s) {
      a0[s] = expf(scores[s] - m0);      s0 += a0[s];
      a1[s] = expf(scores[30 + s] - m1); s1 += a1[s];
    }
    float i0 = 1.f / s0, i1 = 1.f / s1;
    #pragma unroll
    for (int s = 0; s < TAPE_N; ++s) { a0[s] *= i0; a1[s] *= i1; }
  }

  // layer-0 gate rows + u1 rows (one row per thread: gate=tid>>4, cell=j0+(tid&15))
  const int row = (tid >> 4) * 1024 + j0 + (tid & 15);
  float gv = XI0[(size_t)t * 4096 + row];
  float uv = 0.f;
  #pragma unroll
  for (int s = 0; s < TAPE_N; ++s) {
    gv += a0[s] * P0[s * 4096 + row];
    uv += a1[s] * P1[s * 4096 + row];
  }
  u1b[row] = uv;

  __shared__ float gls[64];
  __shared__ float nc0s[16];
  gls[tid] = gv;

  // tape-weighted sums (reads happen before any tape writes below)
  float acc = 0.f;
  if (tid < 16) {
    int j = j0 + tid;
    #pragma unroll
    for (int s = 0; s < TAPE_N; ++s) acc += a0[s] * tapeh[s * 2048 + j];
    newh[(t & 1) * 2048 + j] = acc;
  } else if (tid < 32) {
    int j = j0 + tid - 16;
    #pragma unroll
    for (int s = 0; s < TAPE_N; ++s) acc += a0[s] * tapec[s * 2048 + j];
    nc0s[tid - 16] = acc;
  } else if (tid < 48) {
    int j = j0 + tid - 32;
    #pragma unroll
    for (int s = 0; s < TAPE_N; ++s) acc += a1[s] * tapeh[s * 2048 + 1024 + j];
    newh[(t & 1) * 2048 + 1024 + j] = acc;
  } else {
    int j = j0 + tid - 48;
    #pragma unroll
    for (int s = 0; s < TAPE_N; ++s) acc += a1[s] * tapec[s * 2048 + 1024 + j];
    newc1[j] = acc;
  }
  __syncthreads();

  if (tid < 16) {
    int j = j0 + tid;
    float gi = gls[tid], gf = gls[16 + tid], gg = gls[32 + tid], go = gls[48 + tid];
    float c0 = sigf(gf) * nc0s[tid] + sigf(gi) * tanhf(gg);
    float h0 = sigf(go) * tanhf(c0);
    int tm = t % 30;
    h0cur[j] = h0;
    tapeh[tm * 2048 + j] = h0;
    tapec[tm * 2048 + j] = c0;
  }
}

// ---------------------------------------------------------------------------
// Scan kernel C (grid 256 x 256): g1 = w_ih1@h0 + u1 + biases -> h1/c1 -> tape, out
// ---------------------------------------------------------------------------
__global__ __launch_bounds__(256) void scanC_k(
    const float* __restrict__ wih1, const float* __restrict__ h0cur,
    const float* __restrict__ u1b, const float* __restrict__ bih1,
    const float* __restrict__ bhh1, const float* __restrict__ newc1,
    float* __restrict__ tapeh, float* __restrict__ tapec,
    float* __restrict__ out, int t)
{
  const int tid = threadIdx.x;
  const int w = blockIdx.x;            // cells 4w .. 4w+3
  __shared__ float hs[1024];
  ((float4*)hs)[tid] = ((const float4*)h0cur)[tid];
  __syncthreads();

  int idx  = tid >> 4;                 // 0..15: gate = idx>>2, jj = idx&3
  int lane = tid & 15;
  int gate = idx >> 2, jj = idx & 3;
  int j = w * 4 + jj;
  int row = gate * 1024 + j;
  const float* wr = wih1 + (size_t)row * 1024;
  float acc = 0.f;
  #pragma unroll
  for (int k = 0; k < 16; ++k) {
    float4 wv = *(const float4*)(wr + lane * 4 + k * 64);
    float4 h4 = *(const float4*)(hs + lane * 4 + k * 64);
    acc += wv.x * h4.x + wv.y * h4.y + wv.z * h4.z + wv.w * h4.w;
  }
  #pragma unroll
  for (int o = 8; o >= 1; o >>= 1) acc += __shfl_xor(acc, o, 64);

  __shared__ float gls[16];
  if (lane == 0) gls[idx] = acc + bih1[row] + bhh1[row] + u1b[row];
  __syncthreads();

  if (tid < 4) {
    int j2 = w * 4 + tid;
    float gi = gls[0 * 4 + tid], gf = gls[1 * 4 + tid];
    float gg = gls[2 * 4 + tid], go = gls[3 * 4 + tid];
    float c1 = sigf(gf) * newc1[j2] + sigf(gi) * tanhf(gg);
    float h1 = sigf(go) * tanhf(c1);
    int tm = t % 30;
    tapeh[tm * 2048 + 1024 + j2] = h1;
    tapec[tm * 2048 + 1024 + j2] = c1;
    out[(size_t)(t - TAPE_N) * 1024 + j2] = h1;
  }
}

// ---------------------------------------------------------------------------
extern "C" void kernel_launch(void* const* d_in, const int* in_sizes, int n_in,
                              void* d_out, int out_size, void* d_ws, size_t ws_size,
                              hipStream_t stream) {
  (void)in_sizes; (void)n_in; (void)out_size; (void)ws_size;
  const float* xs    = (const float*)d_in[0];   // [512][1024]
  const float* w_ih  = (const float*)d_in[1];   // [2][4096][1024]
  const float* w_hh  = (const float*)d_in[2];   // [2][4096][1024]
  const float* b_ih  = (const float*)d_in[3];   // [2][4096]
  const float* b_hh  = (const float*)d_in[4];   // [2][4096]
  const float* a_wh  = (const float*)d_in[5];   // [2][1024][1024]
  const float* a_wx  = (const float*)d_in[6];   // [2][1024][1024]
  const float* a_wht = (const float*)d_in[7];   // [2][1024][1024]
  const float* a_v   = (const float*)d_in[8];   // [2][1024]
  float* out = (float*)d_out;                   // [512][1024]

  float* ws    = (float*)d_ws;                  // ~14.1 MB used
  float* XI0   = ws;                            // 512*4096
  float* XA    = XI0   + 512 * 4096;            // 512*2048
  float* tapeh = XA    + 512 * 2048;            // 30*2048  [slot][layer][h]
  float* tapec = tapeh + 30 * 2048;             // 30*2048
  float* P0    = tapec + 30 * 2048;             // 30*4096  [slot][row]
  float* P1    = P0    + 30 * 4096;             // 30*4096
  float* diag  = P1    + 30 * 4096;             // 4096 (dwh[2][1024], dwht[2][1024])
  float* scor  = diag  + 4096;                  // 64
  float* newh  = scor  + 64;                    // 2*2048 parity buffer
  float* h0cur = newh  + 4096;                  // 1024
  float* u1b   = h0cur + 1024;                  // 4096
  float* newc1 = u1b   + 4096;                  // 1024
  float* h0p1  = newc1 + 1024;                  // 30*1024
  float* G1b   = h0p1  + 30 * 1024;             // 30*4096

  // out rows 482..511 are never written by the scan -> zero them every launch
  hipMemsetAsync(out + (size_t)482 * 1024, 0, 30 * 1024 * sizeof(float), stream);
  // prev_h parity buffer: both slots zero (t=30 reads slot 1 as the zero init)
  hipMemsetAsync(newh, 0, 2 * 2048 * sizeof(float), stream);

  diag_k<<<8, 256, 0, stream>>>(a_wh, a_wht, diag);

  // XI0[t][r] = w_ih0 @ x_t + b_ih0 + b_hh0, all 512 t
  gemm_nt<<<dim3(64, 8), 256, 0, stream>>>(w_ih, xs, XI0, b_ih, b_hh, 512, 1024, 4096);
  // XA[t][l][:] = attn_wx[l] @ x_t
  gemm_nt<<<dim3(16, 8), 256, 0, stream>>>(a_wx, xs, XA, nullptr, nullptr, 512, 1024, 2048);
  gemm_nt<<<dim3(16, 8), 256, 0, stream>>>(a_wx + LSTRIDE / 4, xs, XA + 1024, nullptr, nullptr, 512, 1024, 2048);

  // phase 1: layer 0 from XI0 (zero state)
  phase1_l0_k<<<30, 256, 0, stream>>>(XI0, tapeh, tapec, h0p1);
  // G1[t][r] = w_ih1 @ h0_p1[t] + b_ih1 + b_hh1
  gemm_nt<<<dim3(64, 1), 256, 0, stream>>>(w_ih + LSTRIDE, h0p1, G1b, b_ih + 4096, b_hh + 4096, 30, 1024, 4096);
  phase1_l1_k<<<30, 256, 0, stream>>>(G1b, tapeh, tapec);

  // initial P matrices: P{0,1}[s][r] = w_hh{0,1}[r,:] @ tape_h[s, {0,1}, :]
  gemm_nt<<<dim3(64, 1), 256, 0, stream>>>(w_hh, tapeh, P0, nullptr, nullptr, 30, 2048, 4096);
  gemm_nt<<<dim3(64, 1), 256, 0, stream>>>(w_hh + LSTRIDE, tapeh + 1024, P1, nullptr, nullptr, 30, 2048, 4096);

  // sequential scan t = 30 .. 511
  for (int t = TAPE_N; t < T_STEPS; ++t) {
    scanA_k<<<316, 256, 0, stream>>>(tapeh, XA, newh, diag, a_v, w_hh, scor, P0, P1, t);
    scanB_k<<<64, 64, 0, stream>>>(scor, XI0, P0, P1, tapeh, tapec, h0cur, u1b, newh, newc1, t);
    scanC_k<<<256, 256, 0, stream>>>(w_ih + LSTRIDE, h0cur, u1b, b_ih + 4096, b_hh + 4096,
                                     newc1, tapeh, tapec, out, t);
  }
}